// Round 6
// baseline (2808.746 us; speedup 1.0000x reference)
//
#include <hip/hip_runtime.h>
#include <hip/hip_fp16.h>
#include <stdint.h>

// MDRNN: 2-level bidirectional LSTM, S=2048 steps, B=64, H=128, I=256, O=88.
// Scan v12: 4-wave WGs (was 8). Rationale: v11's period was dominated by LDS
// read-pipe occupancy (16 waves/CU x 4 ds_read_b128/step = 64 instrs ~768 cy
// at 12cy/b128), not VALU issue. 4 waves x 8 tiles each (32 MFMA/wave-step,
// w[8][4] resident, waves_per_eu(1,1) for the register budget) cuts LDS reads
// to 16/CU-step and halves barrier population. Each lane owns TWO (unit,gate)
// pairs (units u1, u1+16); tail = 2x{select, inject, 2-trans act}, 8 DPP quad
// broadcasts, 2 cells. G granules in 4-step blocks [b][s/4][d][u][s%4][gate]
// so prefetch fits in 32 VGPRs (gc/gn = 8 uint4).

typedef _Float16 f16;
typedef _Float16 f16x4 __attribute__((ext_vector_type(4)));
typedef _Float16 f16x8 __attribute__((ext_vector_type(8)));
typedef float f32x4 __attribute__((ext_vector_type(4)));

#if defined(__has_builtin)
#if __has_builtin(__builtin_amdgcn_rcpf)
#define FRCP(x) __builtin_amdgcn_rcpf(x)
#else
#define FRCP(x) (1.f / (x))
#endif
#if __has_builtin(__builtin_amdgcn_exp2f)
#define FEXP2(x) __builtin_amdgcn_exp2f(x)
#else
#define FEXP2(x) __exp2f(x)
#endif
#endif

#define K_SIG 1.4426950409f
#define K_TANH 2.8853900818f

template <int CTRL>
static __device__ __forceinline__ float qperm(float v) {
    int r = __builtin_amdgcn_update_dpp(0, __builtin_bit_cast(int, v), CTRL, 0xf, 0xf, true);
    return __builtin_bit_cast(float, r);
}

// ---------------- conversions ----------------

__global__ __launch_bounds__(256) void k_convert_x(const float* __restrict__ x,
                                                   f16* __restrict__ xh) {
    size_t id = (size_t)blockIdx.x * 256 + threadIdx.x;  // 4,194,304 threads x 8 elems
    const float4* src = (const float4*)(x + id * 8);
    float4 v0 = src[0], v1 = src[1];
    f16x8 o = {(f16)v0.x, (f16)v0.y, (f16)v0.z, (f16)v0.w,
               (f16)v1.x, (f16)v1.y, (f16)v1.z, (f16)v1.w};
    *(f16x8*)(xh + id * 8) = o;
}

// Permute rows gate-major -> unit-major-gate-minor and scale by the activation
// log2 constant WITH SIGN: gates i,f,o (0,1,3) -> -log2e (sigmoid computed as
// rcp(1+exp2(v))), gate g (2) -> +2log2e (tanh as 1-2*rcp(1+exp2(v))).
// rp = permuted row (0..1023): d=rp>>9, unit=(rp>>2)&127, gate=rp&3;
// orig row = d*512 + gate*128 + unit. K = 8<<ksh.
__global__ __launch_bounds__(256) void k_convert_wp(const float* __restrict__ src,
                                                    f16* __restrict__ dst, int ksh, int n8) {
    int id = blockIdx.x * 256 + threadIdx.x;
    if (id >= n8) return;
    int rp = id >> ksh;
    int kb = id & ((1 << ksh) - 1);
    int dd = rp >> 9, gi = rp & 3, q = (rp >> 2) & 127;
    float sc = (gi == 2) ? K_TANH : -K_SIG;
    size_t so = ((size_t)(dd * 512 + gi * 128 + q) << (ksh + 3)) + kb * 8;
    const float4* sp = (const float4*)(src + so);
    float4 v0 = sp[0], v1 = sp[1];
    f16x8 o = {(f16)(v0.x * sc), (f16)(v0.y * sc), (f16)(v0.z * sc), (f16)(v0.w * sc),
               (f16)(v1.x * sc), (f16)(v1.y * sc), (f16)(v1.z * sc), (f16)(v1.w * sc)};
    *(f16x8*)(dst + (size_t)id * 8) = o;
}

__global__ __launch_bounds__(256) void k_bias(const float* __restrict__ a,
                                              const float* __restrict__ b,
                                              float* __restrict__ o) {
    int rp = blockIdx.x * 256 + threadIdx.x;   // 1024
    int dd = rp >> 9, gi = rp & 3, q = (rp >> 2) & 127;
    int orig = dd * 512 + gi * 128 + q;
    float sc = (gi == 2) ? K_TANH : -K_SIG;
    o[rp] = (a[orig] + b[orig]) * sc;
}

// ---------------- MFMA GEMM: C = A(W' rows) x B(acts)^T, scan-block output ---
// A = W' [1024][256] (permuted+scaled rows), B = acts [131072][256].
// G layout: [b][s>>2][d][u][s&3][gate] f16 -> f16x4 stores; scan reads 32B per
// (thread, unit, 4-step block).

#define BM 128
#define BN 128
#define BKK 32
#define LDT 40   // padded LDS row stride (fp16 elems)

__global__ __launch_bounds__(256) void k_gemm(const f16* __restrict__ A,
                                              const f16* __restrict__ B,
                                              f16* __restrict__ C,
                                              const float* __restrict__ bsum,
                                              int M, int N, int K) {
    __shared__ __align__(16) f16 As[BM * LDT];
    __shared__ __align__(16) f16 Bs[BN * LDT];
    const int tid  = threadIdx.x;
    const int m0   = blockIdx.x * BM;
    const int n0   = blockIdx.y * BN;
    const int lane = tid & 63;
    const int wave = tid >> 6;
    const int wm   = (wave & 1) * 64;
    const int wn   = (wave >> 1) * 64;
    const int r    = tid >> 1;
    const int koff = (tid & 1) * 16;
    const int mrow = lane & 15;
    const int kof  = (lane >> 4) * 8;
    const int crow = (lane >> 4) * 4;

    f32x4 acc[4][4];
#pragma unroll
    for (int i = 0; i < 4; ++i)
#pragma unroll
        for (int j = 0; j < 4; ++j) acc[i][j] = (f32x4){0.f, 0.f, 0.f, 0.f};

    for (int k0 = 0; k0 < K; k0 += BKK) {
        uint4 a0 = *(const uint4*)(A + (size_t)(m0 + r) * K + k0 + koff);
        uint4 a1 = *(const uint4*)(A + (size_t)(m0 + r) * K + k0 + koff + 8);
        uint4 b0 = *(const uint4*)(B + (size_t)(n0 + r) * K + k0 + koff);
        uint4 b1 = *(const uint4*)(B + (size_t)(n0 + r) * K + k0 + koff + 8);
        *(uint4*)(As + r * LDT + koff)     = a0;
        *(uint4*)(As + r * LDT + koff + 8) = a1;
        *(uint4*)(Bs + r * LDT + koff)     = b0;
        *(uint4*)(Bs + r * LDT + koff + 8) = b1;
        __syncthreads();
        f16x8 af[4], bfr[4];
#pragma unroll
        for (int i = 0; i < 4; ++i)
            af[i] = *(const f16x8*)(As + (wm + i * 16 + mrow) * LDT + kof);
#pragma unroll
        for (int j = 0; j < 4; ++j)
            bfr[j] = *(const f16x8*)(Bs + (wn + j * 16 + mrow) * LDT + kof);
#pragma unroll
        for (int i = 0; i < 4; ++i)
#pragma unroll
            for (int j = 0; j < 4; ++j)
                acc[i][j] = __builtin_amdgcn_mfma_f32_16x16x32_f16(af[i], bfr[j], acc[i][j], 0, 0, 0);
        __syncthreads();
    }
#pragma unroll
    for (int i = 0; i < 4; ++i) {
        const int rb = m0 + wm + i * 16 + crow;          // 4-aligned permuted row
        const float4 bbv = *(const float4*)(bsum + rb);  // bias for gates 0..3
        const int dd = rb >> 9;
        const int uu = (rb & 511) >> 2;                  // unit 0..127
#pragma unroll
        for (int j = 0; j < 4; ++j) {
            const int cm = n0 + wn + j * 16 + (lane & 15);
            const int b  = cm >> 11;          // batch
            const int s  = cm & 2047;         // step
            f16x4 v = {(f16)(acc[i][j][0] + bbv.x), (f16)(acc[i][j][1] + bbv.y),
                       (f16)(acc[i][j][2] + bbv.z), (f16)(acc[i][j][3] + bbv.w)};
            size_t fofs = ((((size_t)b * 512 + (s >> 2)) * 2 + dd) * 128 + uu) * 16
                          + (s & 3) * 4;
            *(f16x4*)(C + fofs) = v;
        }
    }
}

// ---------------- recurrent LSTM scan (MFMA, 1 chain/WG, 4 waves) ----------
// WG = (batch b, dir d), 256 thr. Wave wv owns tiles 8wv..8wv+7 (units
// 32wv..32wv+31). Lane (hi,ch): pair1 = (unit (8wv+(ch>>2))*4+hi, gate ch&3),
// pair2 = same +16 units. 32 MFMA/step/wave (8 indep chains of 4). Tail:
// 2x{12+3 cndmask select, G inject, rcp(1+exp2) act}, 8 DPP quad-broadcasts,
// 2 cell updates. h: 16-slot LDS ring, 4x ds_read_b128 per wave per step.
// MODE 1: stream tout; MODE 2: hfin.

template <int MODE>
__global__ void __attribute__((amdgpu_flat_work_group_size(256, 256),
                               amdgpu_waves_per_eu(1, 1))) k_lstm(
    const f16* __restrict__ G,              // [b][s/4][d][u][s%4][g] f16
    const f16* __restrict__ Whh,            // [1024][128] permuted+scaled
    f16* __restrict__ tout,                 // [131072][256] (MODE 1)
    float* __restrict__ hfin,               // [64][256] f32 (MODE 2)
    const int S) {
    const int wg = blockIdx.x;              // 128
    const int b  = wg >> 1, d = wg & 1;
    const int t  = threadIdx.x;
    const int l  = t & 63, wv = t >> 6;
    const int hi = l >> 4, ch = l & 15;
    const int tt = ch >> 2, g = ch & 3;

    __shared__ __align__(16) f16 ring[16][128];   // 16 slots x 256B

    // resident A-frags: w[q][ks] = tile (8wv+q), row sub=ch, k = ks*32+hi*8
    f16x8 w[8][4];
#pragma unroll
    for (int q = 0; q < 8; ++q)
#pragma unroll
        for (int ks = 0; ks < 4; ++ks)
            w[q][ks] = *(const f16x8*)(Whh + ((size_t)d * 512 + (8 * wv + q) * 16 + ch) * 128
                                       + ks * 32 + hi * 8);

    for (int i = t; i < 1024; i += 256) ((uint32_t*)ring)[i] = 0;  // h(-1)=0

    const int u1 = (8 * wv + tt) * 4 + hi;  // pair-1 unit
    const int u2 = u1 + 16;                 // pair-2 unit (tile +4)
    const f16* gp1 = G + (((size_t)b * 512 * 2 + d) * 128 + u1) * 16;
    const f16* gp2 = gp1 + 16 * 16;         // +16 units

    // per-lane constants
    const bool t0 = (tt & 1) != 0, t1 = (tt & 2) != 0;
    const bool r0 = (g & 1) != 0, r1 = (g & 2) != 0;
    const bool pG = (g & 2) != 0;
    const int  shG = (g & 1) * 16;
    const float Aact = (g == 2) ? 1.f : 0.f;
    const float Bact = (g == 2) ? -2.f : 1.f;
    const bool wrt = (g == 0);

    uint4 gc1[2], gn1[2], gc2[2], gn2[2];   // 32B granules: 4 steps x f16x4
#pragma unroll
    for (int k = 0; k < 2; ++k) {
        gc1[k] = *(const uint4*)(gp1 + k * 8);
        gc2[k] = *(const uint4*)(gp2 + k * 8);
    }

    const f32x4 Z = {0.f, 0.f, 0.f, 0.f};
    float c1 = 0.f, c2 = 0.f;
    __syncthreads();

    for (int sb = 0; sb < S; sb += 4) {
        {   // prefetch next block's G granules (in flight across barriers)
            const size_t nb = (size_t)((sb + 4 < S) ? (sb >> 2) + 1 : (sb >> 2));
#pragma unroll
            for (int k = 0; k < 2; ++k) {
                gn1[k] = *(const uint4*)(gp1 + nb * 4096 + k * 8);
                gn2[k] = *(const uint4*)(gp2 + nb * 4096 + k * 8);
            }
        }
        if (MODE == 1 && sb > 0 && t < 128) {   // stream block sb-4 -> tout
            const int jf = t >> 5, of = t & 31;
            uint2 hv = *(const uint2*)(&ring[((sb - 4) & 15) + jf][of * 4]);
            *(uint2*)(tout + ((size_t)b * 2048 + (sb - 4 + jf)) * 256 + d * 128 + of * 4) = hv;
        }
        // hoisted ring bases: all per-step ds offsets are immediates
        const int half = sb & 15;                        // 0,4,8,12
        const f16* rd0 = &ring[(half + 15) & 15][hi * 8];// jj==0 reads slot (sb-1)&15
        const f16* rdc = &ring[half][hi * 8];            // jj>=1: imm (jj-1)*256
        f16* wr1 = &ring[half][u1];                      // write: imm jj*256
        f16* wr2 = &ring[half][u2];
#pragma unroll
        for (int jj = 0; jj < 4; ++jj) {
            const int s = sb + jj;
            const f16* hb = (jj == 0) ? rd0 : (rdc + (jj - 1) * 128);
            f16x8 b0 = *(const f16x8*)(hb);
            f16x8 b1 = *(const f16x8*)(hb + 32);
            f16x8 b2 = *(const f16x8*)(hb + 64);
            f16x8 b3 = *(const f16x8*)(hb + 96);
            f32x4 A0 = __builtin_amdgcn_mfma_f32_16x16x32_f16(w[0][0], b0, Z, 0, 0, 0);
            f32x4 A1 = __builtin_amdgcn_mfma_f32_16x16x32_f16(w[1][0], b0, Z, 0, 0, 0);
            f32x4 A2 = __builtin_amdgcn_mfma_f32_16x16x32_f16(w[2][0], b0, Z, 0, 0, 0);
            f32x4 A3 = __builtin_amdgcn_mfma_f32_16x16x32_f16(w[3][0], b0, Z, 0, 0, 0);
            f32x4 A4 = __builtin_amdgcn_mfma_f32_16x16x32_f16(w[4][0], b0, Z, 0, 0, 0);
            f32x4 A5 = __builtin_amdgcn_mfma_f32_16x16x32_f16(w[5][0], b0, Z, 0, 0, 0);
            f32x4 A6 = __builtin_amdgcn_mfma_f32_16x16x32_f16(w[6][0], b0, Z, 0, 0, 0);
            f32x4 A7 = __builtin_amdgcn_mfma_f32_16x16x32_f16(w[7][0], b0, Z, 0, 0, 0);
            A0 = __builtin_amdgcn_mfma_f32_16x16x32_f16(w[0][1], b1, A0, 0, 0, 0);
            A1 = __builtin_amdgcn_mfma_f32_16x16x32_f16(w[1][1], b1, A1, 0, 0, 0);
            A2 = __builtin_amdgcn_mfma_f32_16x16x32_f16(w[2][1], b1, A2, 0, 0, 0);
            A3 = __builtin_amdgcn_mfma_f32_16x16x32_f16(w[3][1], b1, A3, 0, 0, 0);
            A4 = __builtin_amdgcn_mfma_f32_16x16x32_f16(w[4][1], b1, A4, 0, 0, 0);
            A5 = __builtin_amdgcn_mfma_f32_16x16x32_f16(w[5][1], b1, A5, 0, 0, 0);
            A6 = __builtin_amdgcn_mfma_f32_16x16x32_f16(w[6][1], b1, A6, 0, 0, 0);
            A7 = __builtin_amdgcn_mfma_f32_16x16x32_f16(w[7][1], b1, A7, 0, 0, 0);
            A0 = __builtin_amdgcn_mfma_f32_16x16x32_f16(w[0][2], b2, A0, 0, 0, 0);
            A1 = __builtin_amdgcn_mfma_f32_16x16x32_f16(w[1][2], b2, A1, 0, 0, 0);
            A2 = __builtin_amdgcn_mfma_f32_16x16x32_f16(w[2][2], b2, A2, 0, 0, 0);
            A3 = __builtin_amdgcn_mfma_f32_16x16x32_f16(w[3][2], b2, A3, 0, 0, 0);
            A4 = __builtin_amdgcn_mfma_f32_16x16x32_f16(w[4][2], b2, A4, 0, 0, 0);
            A5 = __builtin_amdgcn_mfma_f32_16x16x32_f16(w[5][2], b2, A5, 0, 0, 0);
            A6 = __builtin_amdgcn_mfma_f32_16x16x32_f16(w[6][2], b2, A6, 0, 0, 0);
            A7 = __builtin_amdgcn_mfma_f32_16x16x32_f16(w[7][2], b2, A7, 0, 0, 0);
            A0 = __builtin_amdgcn_mfma_f32_16x16x32_f16(w[0][3], b3, A0, 0, 0, 0);
            A1 = __builtin_amdgcn_mfma_f32_16x16x32_f16(w[1][3], b3, A1, 0, 0, 0);
            A2 = __builtin_amdgcn_mfma_f32_16x16x32_f16(w[2][3], b3, A2, 0, 0, 0);
            A3 = __builtin_amdgcn_mfma_f32_16x16x32_f16(w[3][3], b3, A3, 0, 0, 0);
            A4 = __builtin_amdgcn_mfma_f32_16x16x32_f16(w[4][3], b3, A4, 0, 0, 0);
            A5 = __builtin_amdgcn_mfma_f32_16x16x32_f16(w[5][3], b3, A5, 0, 0, 0);
            A6 = __builtin_amdgcn_mfma_f32_16x16x32_f16(w[6][3], b3, A6, 0, 0, 0);
            A7 = __builtin_amdgcn_mfma_f32_16x16x32_f16(w[7][3], b3, A7, 0, 0, 0);
            // pair 1: select tile tt from A0..A3, then C-reg by g
            float v1, v2;
            {
                f32x4 X, Y, T;
#pragma unroll
                for (int e = 0; e < 4; ++e) {
                    X[e] = t0 ? A1[e] : A0[e];
                    Y[e] = t0 ? A3[e] : A2[e];
                    T[e] = t1 ? Y[e] : X[e];
                }
                float xx = r0 ? T[1] : T[0];
                float yy = r0 ? T[3] : T[2];
                v1 = r1 ? yy : xx;
            }
            // pair 2: select tile tt from A4..A7
            {
                f32x4 X, Y, T;
#pragma unroll
                for (int e = 0; e < 4; ++e) {
                    X[e] = t0 ? A5[e] : A4[e];
                    Y[e] = t0 ? A7[e] : A6[e];
                    T[e] = t1 ? Y[e] : X[e];
                }
                float xx = r0 ? T[1] : T[0];
                float yy = r0 ? T[3] : T[2];
                v2 = r1 ? yy : xx;
            }
            // inject this lane's gate pre-acts from the G granules
            {
                uint32_t dwA1 = (jj & 1) ? gc1[jj >> 1].z : gc1[jj >> 1].x;
                uint32_t dwB1 = (jj & 1) ? gc1[jj >> 1].w : gc1[jj >> 1].y;
                uint32_t ds1 = pG ? dwB1 : dwA1;
                v1 += (float)__builtin_bit_cast(f16, (uint16_t)(ds1 >> shG));
                uint32_t dwA2 = (jj & 1) ? gc2[jj >> 1].z : gc2[jj >> 1].x;
                uint32_t dwB2 = (jj & 1) ? gc2[jj >> 1].w : gc2[jj >> 1].y;
                uint32_t ds2 = pG ? dwB2 : dwA2;
                v2 += (float)__builtin_bit_cast(f16, (uint16_t)(ds2 >> shG));
            }
            // unified activation: 2 trans each (sign pre-folded into scaling)
            float act1 = __builtin_fmaf(Bact, FRCP(1.f + FEXP2(v1)), Aact);
            float act2 = __builtin_fmaf(Bact, FRCP(1.f + FEXP2(v2)), Aact);
            // quad-broadcast the gates of both units
            float gi1 = qperm<0x00>(act1), gi2 = qperm<0x00>(act2);
            float gf1 = qperm<0x55>(act1), gf2 = qperm<0x55>(act2);
            float gg1 = qperm<0xAA>(act1), gg2 = qperm<0xAA>(act2);
            float go1 = qperm<0xFF>(act1), go2 = qperm<0xFF>(act2);
            c1 = __builtin_fmaf(gf1, c1, gi1 * gg1);
            c2 = __builtin_fmaf(gf2, c2, gi2 * gg2);
            float tc1 = __builtin_fmaf(-2.f, FRCP(1.f + FEXP2(c1 * K_TANH)), 1.f);
            float tc2 = __builtin_fmaf(-2.f, FRCP(1.f + FEXP2(c2 * K_TANH)), 1.f);
            float h1 = go1 * tc1;
            float h2 = go2 * tc2;
            if (wrt) {
                *(wr1 + jj * 128) = (f16)h1;
                *(wr2 + jj * 128) = (f16)h2;
            }
            if (MODE == 2 && s == S - 1 && wrt) {
                hfin[(size_t)b * 256 + d * 128 + u1] = h1;
                hfin[(size_t)b * 256 + d * 128 + u2] = h2;
            }
            // LDS-only drain + barrier: G prefetch stays in flight
            __asm__ __volatile__("s_waitcnt lgkmcnt(0)\n\ts_barrier" ::: "memory");
        }
#pragma unroll
        for (int k = 0; k < 2; ++k) { gc1[k] = gn1[k]; gc2[k] = gn2[k]; }
    }
    if (MODE == 1 && t < 128) {             // flush final block (steps S-4..S-1)
        const int jf = t >> 5, of = t & 31;
        uint2 hv = *(const uint2*)(&ring[((S - 4) & 15) + jf][of * 4]);
        *(uint2*)(tout + ((size_t)b * 2048 + (S - 4 + jf)) * 256 + d * 128 + of * 4) = hv;
    }
}

// ---------------- output projection ----------------

__global__ __launch_bounds__(128) void k_out(const float* __restrict__ hp,  // [64][256]
                                             const float* __restrict__ Wo,  // [88][256]
                                             const float* __restrict__ bo,  // [88]
                                             float* __restrict__ out) {     // [64][88]
    const int b = blockIdx.x;
    const int t = threadIdx.x;
    __shared__ float hs[256];
    hs[t] = hp[b * 256 + t];
    hs[t + 128] = hp[b * 256 + 128 + t];
    __syncthreads();
    if (t < 88) {
        float acc = bo[t];
        const float* wr = Wo + t * 256;
#pragma unroll 4
        for (int k = 0; k < 256; ++k) acc += wr[k] * hs[k];
        out[b * 88 + t] = acc;
    }
}

// ---------------- launch ----------------

extern "C" void kernel_launch(void* const* d_in, const int* in_sizes, int n_in,
                              void* d_out, int out_size, void* d_ws, size_t ws_size,
                              hipStream_t stream) {
    const float* x    = (const float*)d_in[0];
    const float* Wtih = (const float*)d_in[1];
    const float* Wthh = (const float*)d_in[2];
    const float* btih = (const float*)d_in[3];
    const float* bthh = (const float*)d_in[4];
    const float* Wpih = (const float*)d_in[5];
    const float* Wphh = (const float*)d_in[6];
    const float* bpih = (const float*)d_in[7];
    const float* bphh = (const float*)d_in[8];
    const float* Wo   = (const float*)d_in[9];
    const float* bo   = (const float*)d_in[10];

    char* ws = (char*)d_ws;
    f16*   xh    = (f16*)(ws + 0);            //  67,108,864 B  [131072][256]
    f16*   G     = (f16*)(ws + 67108864);     // 268,435,456 B  scan-block layout
    f16*   tout  = (f16*)(ws + 335544320);    //  67,108,864 B  [131072][256]
    f16*   wtih  = (f16*)(ws + 402653184);    //     524,288 B  permuted+scaled
    f16*   wthh  = (f16*)(ws + 403177472);    //     262,144 B
    f16*   wpih  = (f16*)(ws + 403439616);    //     524,288 B
    f16*   wphh  = (f16*)(ws + 403963904);    //     262,144 B
    float* bsT   = (float*)(ws + 404226048);  //       4,096 B
    float* bsP   = (float*)(ws + 404230144);  //       4,096 B
    float* hp    = (float*)(ws + 404226048);  //      65,536 B  (written by scan2)

    k_convert_x<<<16384, 256, 0, stream>>>(x, xh);
    k_convert_wp<<<128, 256, 0, stream>>>(Wtih, wtih, 5, 32768);
    k_convert_wp<<<64,  256, 0, stream>>>(Wthh, wthh, 4, 16384);
    k_convert_wp<<<128, 256, 0, stream>>>(Wpih, wpih, 5, 32768);
    k_convert_wp<<<64,  256, 0, stream>>>(Wphh, wphh, 4, 16384);
    k_bias<<<4, 256, 0, stream>>>(btih, bthh, bsT);
    k_bias<<<4, 256, 0, stream>>>(bpih, bphh, bsP);

    // G = (xh @ Wt_ih'^T) + bias, scan-block layout
    k_gemm<<<dim3(8, 1024), 256, 0, stream>>>(wtih, xh, G, bsT, 1024, 131072, 256);
    // time-level scan -> tout
    k_lstm<1><<<128, 256, 0, stream>>>(G, wthh, tout, nullptr, 2048);
    // G = (tout @ Wp_ih'^T) + bias
    k_gemm<<<dim3(8, 1024), 256, 0, stream>>>(wpih, tout, G, bsP, 1024, 131072, 256);
    // pitch-level scan -> final h
    k_lstm<2><<<128, 256, 0, stream>>>(G, wphh, nullptr, hp, 2048);
    // output projection
    k_out<<<64, 128, 0, stream>>>(hp, Wo, bo, (float*)d_out);
}